// Round 4
// baseline (444.446 us; speedup 1.0000x reference)
//
#include <hip/hip_runtime.h>

using u16 = unsigned short;
using u32 = unsigned int;
typedef __bf16 bf16x8 __attribute__((ext_vector_type(8)));
typedef float f32x4 __attribute__((ext_vector_type(4)));
typedef float f32x16 __attribute__((ext_vector_type(16)));

__device__ __forceinline__ u16 f2bf(float f) {
  u32 u = __float_as_uint(f);
  u += 0x7FFFu + ((u >> 16) & 1u);
  return (u16)(u >> 16);
}

__device__ __forceinline__ u32 cvtpk(float a, float b) {
  u32 r;
  asm("v_cvt_pk_bf16_f32 %0, %1, %2" : "=v"(r) : "v"(a), "v"(b));
  return r;
}

__device__ __forceinline__ void gload16(const u16* g, u16* l) {
  __builtin_amdgcn_global_load_lds((const __attribute__((address_space(1))) void*)g,
                                   (__attribute__((address_space(3))) void*)l, 16, 0, 0);
}

// ---------------- conversion kernels ----------------
// A_all [768][2048]: rows 0..615 = enc, 640..671 = ip, rest zero.
__global__ void build_a_all(const float* __restrict__ enc, const float* __restrict__ ip,
                            u16* __restrict__ out) {
  const int i = blockIdx.x * 256 + threadIdx.x;
  const int row = i >> 9;
  const int c4 = i & 511;
  ushort4 o = {0, 0, 0, 0};
  const float4* src = nullptr;
  if (row < 616) src = (const float4*)enc + (size_t)row * 512 + c4;
  else if (row >= 640 && row < 672) src = (const float4*)ip + (size_t)(row - 640) * 512 + c4;
  if (src) {
    const float4 v = *src;
    o.x = f2bf(v.x); o.y = f2bf(v.y); o.z = f2bf(v.z); o.w = f2bf(v.w);
  }
  ((ushort4*)out)[i] = o;
}

// 4 x (f32 [2048][1280] -> bf16 [1280][2048]), z selects weight
__global__ void transpose_w4(const float* __restrict__ s0, const float* __restrict__ s1,
                             const float* __restrict__ s2, const float* __restrict__ s3,
                             u16* __restrict__ dst) {
  __shared__ float tile[32][33];
  const int z = blockIdx.z;
  const float* in = (z == 0) ? s0 : (z == 1) ? s1 : (z == 2) ? s2 : s3;
  u16* out = dst + (size_t)z * 1280 * 2048;
  const int K = 2048, N = 1280;
  const int n0 = blockIdx.x << 5, k0 = blockIdx.y << 5;
  const int x = threadIdx.x, y = threadIdx.y;  // (32, 8)
#pragma unroll
  for (int i = 0; i < 32; i += 8)
    tile[y + i][x] = in[(size_t)(k0 + y + i) * N + n0 + x];
  __syncthreads();
#pragma unroll
  for (int i = 0; i < 32; i += 8)
    out[(size_t)(n0 + y + i) * K + k0 + x] = f2bf(tile[x][y + i]);
}

// 2 x (f32 [1280][1280] -> bf16 [1280][1280]), z selects
__global__ void transpose_w2(const float* __restrict__ s0, const float* __restrict__ s1,
                             u16* __restrict__ d0, u16* __restrict__ d1) {
  __shared__ float tile[32][33];
  const int z = blockIdx.z;
  const float* in = z ? s1 : s0;
  u16* out = z ? d1 : d0;
  const int K = 1280, N = 1280;
  const int n0 = blockIdx.x << 5, k0 = blockIdx.y << 5;
  const int x = threadIdx.x, y = threadIdx.y;
#pragma unroll
  for (int i = 0; i < 32; i += 8)
    tile[y + i][x] = in[(size_t)(k0 + y + i) * N + n0 + x];
  __syncthreads();
#pragma unroll
  for (int i = 0; i < 32; i += 8)
    out[(size_t)(n0 + y + i) * K + k0 + x] = f2bf(tile[x][y + i]);
}

// ---------------- 256x256 4-phase pipelined GEMM ----------------
// C[M][N] = A[M][K] * Bt[N][K]^T.  M%256==0, N%256==0, K%64==0.
// AF32: A read as f32 and converted in-flight (reg-staged, swizzled ds_write).
#define MFMA16(a, b, c) __builtin_amdgcn_mfma_f32_16x16x32_bf16(a, b, c, 0, 0, 0)
#define MFMA32(a, b, c) __builtin_amdgcn_mfma_f32_32x32x16_bf16(a, b, c, 0, 0, 0)

template <int F32OUT, int AF32>
__global__ __launch_bounds__(512, 2) void gemm256(
    const u16* __restrict__ A, const float* __restrict__ Af, const u16* __restrict__ Bt,
    u16* __restrict__ Cb, float* __restrict__ Cf, const float* __restrict__ bias,
    int M, int N, int K) {
  __shared__ __align__(16) u16 smem[65536];
  u16* As = smem;
  u16* Bs = smem + 32768;

  const int tid = threadIdx.x;
  const int w = tid >> 6, lane = tid & 63;
  const int lo = lane & 15, hi = lane >> 4;
  const int wm = w >> 2, wn = w & 3;

  const int nbn = N >> 8;
  int wg = blockIdx.x;
  {  // bijective XCD swizzle (m204)
    const int nwg = gridDim.x;
    const int q = nwg >> 3, r = nwg & 7;
    const int xcd = wg & 7, l = wg >> 3;
    wg = (xcd < r ? xcd * (q + 1) : r * (q + 1) + (xcd - r) * q) + l;
  }
  const int bm = wg / nbn, bn = wg % nbn;
  const int m0 = bm << 8, n0 = bn << 8;
  const int NT = K >> 6;

  const int sr = lane >> 3;
  const int sc8 = ((lane & 7) ^ sr) << 3;  // pre-swizzled col (gload_lds path)
  const int c8l = (lane & 7) << 3;         // linear col (reg-staged path)
  const int swz8 = ((lane & 7) ^ sr) << 3; // swizzled LDS col (reg-staged path)
  const u16* pA[2];
  const u16* pB[2];
#pragma unroll
  for (int i = 0; i < 2; ++i) {
    const int rr = (i * 8 + w) * 8 + sr;
    pA[i] = A + (size_t)(m0 + rr) * K + sc8;
    pB[i] = Bt + (size_t)(n0 + rr) * K + sc8;
  }
  const int ch0 = w * 512, ch1 = (8 + w) * 512;

#define STAGE_A(h, tt)                                                     \
  {                                                                        \
    const int ttc = ((tt) < NT) ? (tt) : (NT - 1);                         \
    u16* d = As + ((((tt)&1) * 2 + (h)) << 13);                            \
    const size_t off = (size_t)(h)*128 * K + (size_t)ttc * 64;             \
    gload16(pA[0] + off, d + ch0);                                         \
    gload16(pA[1] + off, d + ch1);                                         \
  }
#define STAGE_B(h, tt)                                                     \
  {                                                                        \
    const int ttc = ((tt) < NT) ? (tt) : (NT - 1);                         \
    u16* d = Bs + ((((tt)&1) * 2 + (h)) << 13);                            \
    const size_t off = (size_t)(h)*128 * K + (size_t)ttc * 64;             \
    gload16(pB[0] + off, d + ch0);                                         \
    gload16(pB[1] + off, d + ch1);                                         \
  }

  // reg-staged f32 A: 8 global dwordx4 loads -> 16 cvt_pk -> 4 ds_write_b128
  float4 fAr[2][2][2];
#define LOADA_F32(tt)                                                      \
  {                                                                        \
    const int ttc = ((tt) < NT) ? (tt) : (NT - 1);                         \
    _Pragma("unroll") for (int h = 0; h < 2; ++h)                          \
    _Pragma("unroll") for (int i = 0; i < 2; ++i) {                        \
      const int rr = (i * 8 + w) * 8 + sr;                                 \
      const float* s = Af + (size_t)(m0 + h * 128 + rr) * K +              \
                       (size_t)ttc * 64 + c8l;                             \
      fAr[h][i][0] = *(const float4*)s;                                    \
      fAr[h][i][1] = *(const float4*)(s + 4);                              \
    }                                                                      \
  }
#define WRITEA(tt)                                                         \
  {                                                                        \
    _Pragma("unroll") for (int h = 0; h < 2; ++h)                          \
    _Pragma("unroll") for (int i = 0; i < 2; ++i) {                        \
      const int rr = (i * 8 + w) * 8 + sr;                                 \
      u16* d = As + ((((tt)&1) * 2 + h) << 13) + rr * 64 + swz8;           \
      union { u32 u[4]; bf16x8 v; } pk;                                    \
      pk.u[0] = cvtpk(fAr[h][i][0].x, fAr[h][i][0].y);                     \
      pk.u[1] = cvtpk(fAr[h][i][0].z, fAr[h][i][0].w);                     \
      pk.u[2] = cvtpk(fAr[h][i][1].x, fAr[h][i][1].y);                     \
      pk.u[3] = cvtpk(fAr[h][i][1].z, fAr[h][i][1].w);                     \
      *(bf16x8*)d = pk.v;                                                  \
    }                                                                      \
  }

  const int low0 = (lo << 7) | ((hi ^ (lo & 7)) << 4);
  const int low1 = (lo << 7) | (((4 | hi) ^ (lo & 7)) << 4);

  f32x4 acc[8][4];
#pragma unroll
  for (int i = 0; i < 8; ++i)
#pragma unroll
    for (int j = 0; j < 4; ++j) acc[i][j] = (f32x4){0.f, 0.f, 0.f, 0.f};

  // prologue
  if (AF32) {
    STAGE_B(0, 0); STAGE_B(1, 0);
    LOADA_F32(0);
    STAGE_B(0, 1); STAGE_B(1, 1);
    WRITEA(0);
  } else {
    STAGE_B(0, 0); STAGE_B(1, 0);
    STAGE_A(0, 0); STAGE_A(1, 0);
    STAGE_B(0, 1); STAGE_B(1, 1);
  }

  const char* aSm = (const char*)As;
  const char* bSm = (const char*)Bs;

  for (int t = 0; t < NT; ++t) {
    const int p = t & 1;
    const int aBase = (p * 2 + wm) << 14;
    const int bBase = ((p * 2 + (wn >> 1)) << 14) + ((wn & 1) << 13);

    if (AF32) asm volatile("s_waitcnt lgkmcnt(0)" ::: "memory");
    asm volatile("s_waitcnt vmcnt(4)" ::: "memory");
    asm volatile("s_barrier" ::: "memory");

    bf16x8 a0[4][2], a1[4][2], b0[2][2], b1[2][2];
    // ---- ph0 ----
#pragma unroll
    for (int mf = 0; mf < 4; ++mf) {
      a0[mf][0] = *(const bf16x8*)(aSm + aBase + (mf << 11) + low0);
      a0[mf][1] = *(const bf16x8*)(aSm + aBase + (mf << 11) + low1);
    }
#pragma unroll
    for (int nf = 0; nf < 2; ++nf) {
      b0[nf][0] = *(const bf16x8*)(bSm + bBase + (nf << 11) + low0);
      b0[nf][1] = *(const bf16x8*)(bSm + bBase + (nf << 11) + low1);
    }
    if (!AF32) STAGE_A(0, t + 1);
    __builtin_amdgcn_s_setprio(1);
#pragma unroll
    for (int mf = 0; mf < 4; ++mf)
#pragma unroll
      for (int nf = 0; nf < 2; ++nf) {
        acc[mf][nf] = MFMA16(a0[mf][0], b0[nf][0], acc[mf][nf]);
        acc[mf][nf] = MFMA16(a0[mf][1], b0[nf][1], acc[mf][nf]);
      }
    __builtin_amdgcn_s_setprio(0);
    asm volatile("s_barrier" ::: "memory");

    // ---- ph1 ----
#pragma unroll
    for (int nf = 0; nf < 2; ++nf) {
      b1[nf][0] = *(const bf16x8*)(bSm + bBase + (1 << 12) + (nf << 11) + low0);
      b1[nf][1] = *(const bf16x8*)(bSm + bBase + (1 << 12) + (nf << 11) + low1);
    }
    if (AF32) { LOADA_F32(t + 1); } else { STAGE_A(1, t + 1); }
    __builtin_amdgcn_s_setprio(1);
#pragma unroll
    for (int mf = 0; mf < 4; ++mf)
#pragma unroll
      for (int nf = 0; nf < 2; ++nf) {
        acc[mf][2 + nf] = MFMA16(a0[mf][0], b1[nf][0], acc[mf][2 + nf]);
        acc[mf][2 + nf] = MFMA16(a0[mf][1], b1[nf][1], acc[mf][2 + nf]);
      }
    __builtin_amdgcn_s_setprio(0);
    asm volatile("s_barrier" ::: "memory");

    // ---- ph2 ----
#pragma unroll
    for (int mf = 0; mf < 4; ++mf) {
      a1[mf][0] = *(const bf16x8*)(aSm + aBase + (1 << 13) + (mf << 11) + low0);
      a1[mf][1] = *(const bf16x8*)(aSm + aBase + (1 << 13) + (mf << 11) + low1);
    }
    STAGE_B(0, t + 2);
    __builtin_amdgcn_s_setprio(1);
#pragma unroll
    for (int mf = 0; mf < 4; ++mf)
#pragma unroll
      for (int nf = 0; nf < 2; ++nf) {
        acc[4 + mf][nf] = MFMA16(a1[mf][0], b0[nf][0], acc[4 + mf][nf]);
        acc[4 + mf][nf] = MFMA16(a1[mf][1], b0[nf][1], acc[4 + mf][nf]);
      }
    __builtin_amdgcn_s_setprio(0);
    asm volatile("s_barrier" ::: "memory");

    // ---- ph3 ----
    STAGE_B(1, t + 2);
    if (AF32) WRITEA(t + 1);
    __builtin_amdgcn_s_setprio(1);
#pragma unroll
    for (int mf = 0; mf < 4; ++mf)
#pragma unroll
      for (int nf = 0; nf < 2; ++nf) {
        acc[4 + mf][2 + nf] = MFMA16(a1[mf][0], b1[nf][0], acc[4 + mf][2 + nf]);
        acc[4 + mf][2 + nf] = MFMA16(a1[mf][1], b1[nf][1], acc[4 + mf][2 + nf]);
      }
    __builtin_amdgcn_s_setprio(0);
  }

  // ---- epilogue ----
#pragma unroll
  for (int g = 0; g < 2; ++g)
#pragma unroll
    for (int mf = 0; mf < 4; ++mf)
#pragma unroll
      for (int ng = 0; ng < 2; ++ng)
#pragma unroll
        for (int nfi = 0; nfi < 2; ++nfi) {
          const f32x4 v = acc[g * 4 + mf][ng * 2 + nfi];
          const int row0 = m0 + wm * 128 + g * 64 + mf * 16 + hi * 4;
          const int col = n0 + wn * 64 + ng * 32 + nfi * 16 + lo;
          if (F32OUT) {
            const float bb = bias[col];
#pragma unroll
            for (int r = 0; r < 4; ++r)
              Cf[(size_t)(row0 + r) * N + col] = v[r] + bb;
          } else {
#pragma unroll
            for (int r = 0; r < 4; ++r)
              Cb[(size_t)(row0 + r) * N + col] = f2bf(v[r]);
          }
        }
#undef STAGE_A
#undef STAGE_B
#undef LOADA_F32
#undef WRITEA
}

// ---------------- VT build: vt[b*20+h][d=64][k=96] from kvc V columns ----------------
__global__ __launch_bounds__(256) void build_vt(const u16* __restrict__ kvc,
                                                u16* __restrict__ vt) {
  __shared__ u16 Ls[96][72];
  const int tid = threadIdx.x;
  const int h = blockIdx.x % 20, b = blockIdx.x / 20;
  for (int idx = tid; idx < 96 * 8; idx += 256) {
    const int row = idx >> 3, c8 = (idx & 7) << 3;
    uint4 val = make_uint4(0, 0, 0, 0);
    if (row < 77)
      val = *(const uint4*)(kvc + (size_t)(b * 77 + row) * 5120 + 1280 + h * 64 + c8);
    else if (row >= 80 && row < 84)
      val = *(const uint4*)(kvc + (size_t)(640 + b * 4 + row - 80) * 5120 + 3840 + h * 64 + c8);
    *(uint4*)&Ls[row][c8] = val;
  }
  __syncthreads();
  u16* dst = vt + (size_t)blockIdx.x * 64 * 96;
  for (int idx = tid; idx < 768; idx += 256) {
    const int d = idx / 12, c = (idx % 12) * 8;
    u16 tmp[8];
#pragma unroll
    for (int j = 0; j < 8; ++j) tmp[j] = Ls[c + j][d];
    *(uint4*)(dst + d * 96 + c) = *(const uint4*)tmp;
  }
}

// ---------------- attention v2: swapped-QK, zero-LDS, wave-independent ----------------
__global__ __launch_bounds__(256) void attn2(
    const u16* __restrict__ Q, const u16* __restrict__ kvc,
    const u16* __restrict__ vt, u16* __restrict__ O) {
  const int tid = threadIdx.x;
  const int w = tid >> 6, lane = tid & 63;
  const int l31 = lane & 31, hi5 = lane >> 5;
  const int bid = blockIdx.x;
  const int qc = bid & 31;
  const int h = (bid >> 5) % 20;
  const int b = bid / 640;
  const int q0 = qc * 128 + w * 32;
  const size_t qrow = (size_t)b * 4096 + q0 + l31;

  bf16x8 qf[4];
  const u16* qp = Q + qrow * 1280 + h * 64 + hi5 * 8;
#pragma unroll
  for (int dc = 0; dc < 4; ++dc) qf[dc] = *(const bf16x8*)(qp + dc * 16);

  f32x16 s[3];
#pragma unroll
  for (int kf = 0; kf < 3; ++kf)
#pragma unroll
    for (int r = 0; r < 16; ++r) s[kf][r] = 0.f;

#pragma unroll
  for (int kf = 0; kf < 3; ++kf) {
    const int key = kf * 32 + l31;
    const u16* kp;
    if (key < 77) kp = kvc + (size_t)(b * 77 + key) * 5120 + h * 64 + hi5 * 8;
    else if (key >= 80 && key < 84)
      kp = kvc + (size_t)(640 + b * 4 + key - 80) * 5120 + 2560 + h * 64 + hi5 * 8;
    else kp = kvc + h * 64 + hi5 * 8;  // masked later
    bf16x8 ka[4];
#pragma unroll
    for (int dc = 0; dc < 4; ++dc) ka[dc] = *(const bf16x8*)(kp + dc * 16);
#pragma unroll
    for (int dc = 0; dc < 4; ++dc) s[kf] = MFMA32(ka[dc], qf[dc], s[kf]);
  }

  float st = 0.f, si = 0.f;
#pragma unroll
  for (int kf = 0; kf < 3; ++kf)
#pragma unroll
    for (int r = 0; r < 16; ++r) {
      const int krem = (r & 3) + 8 * (r >> 2);
      const int k = kf * 32 + krem + 4 * hi5;
      const bool vtx = k < 77;
      const bool vip = (k >= 80) & (k < 84);
      const float e = (vtx | vip) ? __expf(s[kf][r] * 0.125f) : 0.f;
      s[kf][r] = e;
      st += vtx ? e : 0.f;
      si += vip ? e : 0.f;
    }
  st += __shfl_xor(st, 32);
  si += __shfl_xor(si, 32);
  const float rt = __fdividef(1.f, st);
  const float ri = __fdividef(1.f, si);
#pragma unroll
  for (int kf = 0; kf < 3; ++kf)
#pragma unroll
    for (int r = 0; r < 16; ++r) {
      const int krem = (r & 3) + 8 * (r >> 2);
      const int k = kf * 32 + krem + 4 * hi5;
      const bool vip = (k >= 80) & (k < 84);
      s[kf][r] *= vip ? ri : rt;
    }

  f32x16 acc[2];
#pragma unroll
  for (int nf = 0; nf < 2; ++nf)
#pragma unroll
    for (int r = 0; r < 16; ++r) acc[nf][r] = 0.f;

  const u16* vbase = vt + ((size_t)(b * 20 + h) * 64) * 96 + hi5 * 8;
#pragma unroll
  for (int ks = 0; ks < 6; ++ks) {
    const int kf = ks >> 1;
    const int rb = (ks & 1) * 8;
    const u32 lo01 = cvtpk(s[kf][rb + 0], s[kf][rb + 1]);
    const u32 lo23 = cvtpk(s[kf][rb + 2], s[kf][rb + 3]);
    const u32 hi01 = cvtpk(s[kf][rb + 4], s[kf][rb + 5]);
    const u32 hi23 = cvtpk(s[kf][rb + 6], s[kf][rb + 7]);
    const u32 plo01 = __shfl_xor(lo01, 32);
    const u32 plo23 = __shfl_xor(lo23, 32);
    const u32 phi01 = __shfl_xor(hi01, 32);
    const u32 phi23 = __shfl_xor(hi23, 32);
    union { u32 u[4]; bf16x8 v; } pu;
    pu.u[0] = hi5 ? phi01 : lo01;
    pu.u[1] = hi5 ? phi23 : lo23;
    pu.u[2] = hi5 ? hi01 : plo01;
    pu.u[3] = hi5 ? hi23 : plo23;
#pragma unroll
    for (int nf = 0; nf < 2; ++nf) {
      const bf16x8 vb = *(const bf16x8*)(vbase + (size_t)(nf * 32 + l31) * 96 + ks * 16);
      acc[nf] = MFMA32(pu.v, vb, acc[nf]);
    }
  }

#pragma unroll
  for (int nf = 0; nf < 2; ++nf)
#pragma unroll
    for (int r = 0; r < 16; ++r) {
      const int row = q0 + (r & 3) + 8 * (r >> 2) + 4 * hi5;
      O[((size_t)b * 4096 + row) * 1280 + h * 64 + nf * 32 + l31] = f2bf(acc[nf][r]);
    }
}

// ---------------- launch ----------------
extern "C" void kernel_launch(void* const* d_in, const int* in_sizes, int n_in,
                              void* d_out, int out_size, void* d_ws, size_t ws_size,
                              hipStream_t stream) {
  (void)in_sizes; (void)n_in; (void)out_size; (void)ws_size;
  const float* hs   = (const float*)d_in[0];
  const float* enc  = (const float*)d_in[1];
  const float* ip   = (const float*)d_in[2];
  const float* Wq   = (const float*)d_in[3];
  const float* Wk   = (const float*)d_in[4];
  const float* Wv   = (const float*)d_in[5];
  const float* Wkip = (const float*)d_in[6];
  const float* Wvip = (const float*)d_in[7];
  const float* Wo   = (const float*)d_in[8];
  const float* bo   = (const float*)d_in[9];
  float* out = (float*)d_out;

  // d_out (167.8 MB) as scratch: q_bf in first half (dead before final write).
  u16* q_bf = (u16*)d_out;

  // ws layout. wq_t/kvw/a_all overlap the attn region (dead before attn2).
  char* ws = (char*)d_ws;
  u16* kvc   = (u16*)(ws);                         // 15,728,640 B  [768][5120]
  u16* wo_t  = (u16*)(ws + 15728640);              //  3,276,800 B
  u16* vt    = (u16*)(ws + 19005440);              //  1,966,080 B  [160][64][96]
  u16* attn  = (u16*)(ws + 20971520);              // 83,886,080 B
  u16* wq_t  = attn;                               //  3,276,800 B (overlap)
  u16* kvw   = (u16*)(ws + 20971520 + 3276800);    // 20,971,520 B (overlap) [5120][2048]
  u16* a_all = (u16*)(ws + 20971520 + 24248320);   //  3,145,728 B (overlap) [768][2048]

  build_a_all<<<1536, 256, 0, stream>>>(enc, ip, a_all);

  dim3 tb(32, 8);
  transpose_w4<<<dim3(40, 64, 4), tb, 0, stream>>>(Wk, Wv, Wkip, Wvip, kvw);
  transpose_w2<<<dim3(40, 40, 2), tb, 0, stream>>>(Wq, Wo, wq_t, wo_t);

  // Q-proj: A = hs (f32, converted in-flight)
  gemm256<0, 1><<<640, 512, 0, stream>>>(nullptr, hs, wq_t, q_bf, nullptr, nullptr,
                                         32768, 1280, 1280);
  // fused K/V projections
  gemm256<0, 0><<<60, 512, 0, stream>>>(a_all, nullptr, kvw, kvc, nullptr, nullptr,
                                        768, 5120, 2048);

  build_vt<<<160, 256, 0, stream>>>(kvc, vt);

  attn2<<<5120, 256, 0, stream>>>(q_bf, kvc, vt, attn);

  // O-proj + bias (f32 out)
  gemm256<1, 0><<<640, 512, 0, stream>>>(attn, nullptr, wo_t, nullptr, out, bo,
                                         32768, 1280, 1280);
}

// Round 5
// 420.952 us; speedup vs baseline: 1.0558x; 1.0558x over previous
//
#include <hip/hip_runtime.h>

using u16 = unsigned short;
using u32 = unsigned int;
typedef __bf16 bf16x8 __attribute__((ext_vector_type(8)));
typedef float f32x4 __attribute__((ext_vector_type(4)));
typedef float f32x16 __attribute__((ext_vector_type(16)));

__device__ __forceinline__ u16 f2bf(float f) {
  u32 u = __float_as_uint(f);
  u += 0x7FFFu + ((u >> 16) & 1u);
  return (u16)(u >> 16);
}

__device__ __forceinline__ u32 cvtpk(float a, float b) {
  u32 r;
  asm("v_cvt_pk_bf16_f32 %0, %1, %2" : "=v"(r) : "v"(a), "v"(b));
  return r;
}

__device__ __forceinline__ void gload16(const u16* g, u16* l) {
  __builtin_amdgcn_global_load_lds((const __attribute__((address_space(1))) void*)g,
                                   (__attribute__((address_space(3))) void*)l, 16, 0, 0);
}

// ---------------- conversion kernels ----------------
__global__ void f32_to_bf16_vec(const float* __restrict__ in, u16* __restrict__ out, long n4) {
  const long i = (long)blockIdx.x * 256 + threadIdx.x;
  if (i >= n4) return;
  const float4 v = ((const float4*)in)[i];
  ushort4 o;
  o.x = f2bf(v.x); o.y = f2bf(v.y); o.z = f2bf(v.z); o.w = f2bf(v.w);
  ((ushort4*)out)[i] = o;
}

// A_all [768][2048]: rows 0..615 = enc, 640..671 = ip, rest zero.
__global__ void build_a_all(const float* __restrict__ enc, const float* __restrict__ ip,
                            u16* __restrict__ out) {
  const int i = blockIdx.x * 256 + threadIdx.x;
  const int row = i >> 9;
  const int c4 = i & 511;
  ushort4 o = {0, 0, 0, 0};
  const float4* src = nullptr;
  if (row < 616) src = (const float4*)enc + (size_t)row * 512 + c4;
  else if (row >= 640 && row < 672) src = (const float4*)ip + (size_t)(row - 640) * 512 + c4;
  if (src) {
    const float4 v = *src;
    o.x = f2bf(v.x); o.y = f2bf(v.y); o.z = f2bf(v.z); o.w = f2bf(v.w);
  }
  ((ushort4*)out)[i] = o;
}

// 4 x (f32 [2048][1280] -> bf16 [1280][2048]), z selects weight
__global__ void transpose_w4(const float* __restrict__ s0, const float* __restrict__ s1,
                             const float* __restrict__ s2, const float* __restrict__ s3,
                             u16* __restrict__ dst) {
  __shared__ float tile[32][33];
  const int z = blockIdx.z;
  const float* in = (z == 0) ? s0 : (z == 1) ? s1 : (z == 2) ? s2 : s3;
  u16* out = dst + (size_t)z * 1280 * 2048;
  const int K = 2048, N = 1280;
  const int n0 = blockIdx.x << 5, k0 = blockIdx.y << 5;
  const int x = threadIdx.x, y = threadIdx.y;  // (32, 8)
#pragma unroll
  for (int i = 0; i < 32; i += 8)
    tile[y + i][x] = in[(size_t)(k0 + y + i) * N + n0 + x];
  __syncthreads();
#pragma unroll
  for (int i = 0; i < 32; i += 8)
    out[(size_t)(n0 + y + i) * K + k0 + x] = f2bf(tile[x][y + i]);
}

// 2 x (f32 [1280][1280] -> bf16 [1280][1280]), z selects
__global__ void transpose_w2(const float* __restrict__ s0, const float* __restrict__ s1,
                             u16* __restrict__ d0, u16* __restrict__ d1) {
  __shared__ float tile[32][33];
  const int z = blockIdx.z;
  const float* in = z ? s1 : s0;
  u16* out = z ? d1 : d0;
  const int K = 1280, N = 1280;
  const int n0 = blockIdx.x << 5, k0 = blockIdx.y << 5;
  const int x = threadIdx.x, y = threadIdx.y;
#pragma unroll
  for (int i = 0; i < 32; i += 8)
    tile[y + i][x] = in[(size_t)(k0 + y + i) * N + n0 + x];
  __syncthreads();
#pragma unroll
  for (int i = 0; i < 32; i += 8)
    out[(size_t)(n0 + y + i) * K + k0 + x] = f2bf(tile[x][y + i]);
}

// ---------------- 256x256 8-phase pipelined GEMM (m201-style) ----------------
// C[M][N] = A[M][K] * Bt[N][K]^T.  M%256==0, N%256==0, K%128==0 (NT even).
// 512 threads = 8 waves (2M x 4N), wave tile 128x64. LDS 128KB:
// A[2buf][2half][128][64] swizzled (byte^=(row&7)<<4), B same.
// Per iteration: 2 K-tiles (t0=2i -> buf0, t1=2i+1 -> buf1), 8 phases.
// Phase = { ds_read subtile; stage half-tile(s); barrier; lgkmcnt(0);
//           setprio(1) 16 MFMA setprio(0); [vmcnt(6) at ph4/ph8]; barrier }
// Stage slots: ph1:A(t1)h1  ph3:B(t0+2)h0  ph4:A(t0+2)h0,B(t0+2)h1
//              ph5:A(t0+2)h1 ph7:B(t1+2)h0 ph8:A(t1+2)h0,B(t1+2)h1
// WAR: each half's last reader completes at lgkmcnt(0) before the barrier
// preceding its re-stage. RAW: vmcnt(6) leaves exactly the 3 newer
// half-tiles (6 loads) in flight; gated loads issued 3 phases earlier.
#define MFMA16(a, b, c) __builtin_amdgcn_mfma_f32_16x16x32_bf16(a, b, c, 0, 0, 0)
#define MFMA32(a, b, c) __builtin_amdgcn_mfma_f32_32x32x16_bf16(a, b, c, 0, 0, 0)

template <int F32OUT>
__global__ __launch_bounds__(512, 2) void gemm8p(
    const u16* __restrict__ A, const u16* __restrict__ Bt,
    u16* __restrict__ Cb, float* __restrict__ Cf, const float* __restrict__ bias,
    int M, int N, int K) {
  __shared__ __align__(16) u16 smem[65536];
  u16* As = smem;           // bytes [buf<<15 | half<<14 | row*128 | swz k]
  u16* Bs = smem + 32768;

  const int tid = threadIdx.x;
  const int w = tid >> 6, lane = tid & 63;
  const int lo = lane & 15, hi = lane >> 4;
  const int wm = w >> 2, wn = w & 3;

  const int nbn = N >> 8;
  int wg = blockIdx.x;
  {  // bijective XCD swizzle (m204)
    const int nwg = gridDim.x;
    const int q = nwg >> 3, r = nwg & 7;
    const int xcd = wg & 7, l = wg >> 3;
    wg = (xcd < r ? xcd * (q + 1) : r * (q + 1) + (xcd - r) * q) + l;
  }
  const int bm = wg / nbn, bn = wg % nbn;
  const int m0 = bm << 8, n0 = bn << 8;
  const int NT = K >> 6;
  const int NI = NT >> 1;

  // staging: chunk c covers LDS bytes [c*1024, +1024); thread's chunks {w, 8+w}.
  // pre-swizzled global source: row = c*8 + (lane>>3), col8 = ((lane&7)^(lane>>3))*8
  const int sr = lane >> 3;
  const int sc8 = ((lane & 7) ^ sr) << 3;
  const u16* pA[2];
  const u16* pB[2];
#pragma unroll
  for (int i = 0; i < 2; ++i) {
    const int rr = (i * 8 + w) * 8 + sr;
    pA[i] = A + (size_t)(m0 + rr) * K + sc8;
    pB[i] = Bt + (size_t)(n0 + rr) * K + sc8;
  }
  const int ch0 = w * 512, ch1 = (8 + w) * 512;

#define STAGE_A(h, tt)                                                     \
  {                                                                        \
    const int ttc = ((tt) < NT) ? (tt) : (NT - 1);                         \
    u16* d = As + ((((tt)&1) * 2 + (h)) << 13);                            \
    const size_t off = (size_t)(h)*128 * K + (size_t)ttc * 64;             \
    gload16(pA[0] + off, d + ch0);                                         \
    gload16(pA[1] + off, d + ch1);                                         \
  }
#define STAGE_B(h, tt)                                                     \
  {                                                                        \
    const int ttc = ((tt) < NT) ? (tt) : (NT - 1);                         \
    u16* d = Bs + ((((tt)&1) * 2 + (h)) << 13);                            \
    const size_t off = (size_t)(h)*128 * K + (size_t)ttc * 64;             \
    gload16(pB[0] + off, d + ch0);                                         \
    gload16(pB[1] + off, d + ch1);                                         \
  }

  // swizzled ds_read low bytes: row=lo (+16*mf via <<11), kbyte^=(lo&7)<<4
  const int low0 = (lo << 7) | ((hi ^ (lo & 7)) << 4);
  const int low1 = (lo << 7) | (((4 | hi) ^ (lo & 7)) << 4);
  const char* aSm = (const char*)As;
  const char* bSm = (const char*)Bs;
  const int aOff = wm << 14;                          // this wave's A half
  const int bOff = ((wn >> 1) << 14) + ((wn & 1) << 13);

  f32x4 acc[8][4];
#pragma unroll
  for (int i = 0; i < 8; ++i)
#pragma unroll
    for (int j = 0; j < 4; ++j) acc[i][j] = (f32x4){0.f, 0.f, 0.f, 0.f};

  bf16x8 a[4][2], b0[2][2], b1[2][2];

#define RD_A(buf, g)                                                       \
  _Pragma("unroll") for (int mf = 0; mf < 4; ++mf) {                       \
    const char* p_ = aSm + ((buf) << 15) + aOff + ((g) << 13) + (mf << 11);\
    a[mf][0] = *(const bf16x8*)(p_ + low0);                                \
    a[mf][1] = *(const bf16x8*)(p_ + low1);                                \
  }
#define RD_B(buf, h, dst)                                                  \
  _Pragma("unroll") for (int j = 0; j < 2; ++j) {                          \
    const char* p_ = bSm + ((buf) << 15) + bOff + ((h) << 12) + (j << 11); \
    dst[j][0] = *(const bf16x8*)(p_ + low0);                               \
    dst[j][1] = *(const bf16x8*)(p_ + low1);                               \
  }
#define MM(g, h, bb)                                                       \
  __builtin_amdgcn_s_setprio(1);                                           \
  _Pragma("unroll") for (int mf = 0; mf < 4; ++mf)                         \
  _Pragma("unroll") for (int j = 0; j < 2; ++j) {                          \
    acc[(g)*4 + mf][(h)*2 + j] =                                           \
        MFMA16(a[mf][0], bb[j][0], acc[(g)*4 + mf][(h)*2 + j]);            \
    acc[(g)*4 + mf][(h)*2 + j] =                                           \
        MFMA16(a[mf][1], bb[j][1], acc[(g)*4 + mf][(h)*2 + j]);            \
  }                                                                        \
  __builtin_amdgcn_s_setprio(0);
#define BAR_MID()                                                          \
  asm volatile("s_barrier" ::: "memory");                                  \
  asm volatile("s_waitcnt lgkmcnt(0)" ::: "memory");                       \
  __builtin_amdgcn_sched_barrier(0);
#define PH_CLOSE() asm volatile("s_barrier" ::: "memory");
#define PH_CLOSE_GATE()                                                    \
  asm volatile("s_waitcnt vmcnt(6)" ::: "memory");                         \
  asm volatile("s_barrier" ::: "memory");

  // prologue: tile0 (4 halves) + B(1)h0, A(1)h0, B(1)h1  => 14 loads;
  // vmcnt(6) completes exactly tile0. A(1)h1 staged at ph1 of iter 0.
  STAGE_A(0, 0); STAGE_A(1, 0); STAGE_B(0, 0); STAGE_B(1, 0);
  STAGE_B(0, 1); STAGE_A(0, 1); STAGE_B(1, 1);
  asm volatile("s_waitcnt vmcnt(6)" ::: "memory");
  asm volatile("s_barrier" ::: "memory");

  for (int i = 0; i < NI; ++i) {
    const int t0 = i << 1;
    // ---- ph1: t0 q(0,0) ----
    RD_A(0, 0); RD_B(0, 0, b0);
    STAGE_A(1, t0 + 1);
    BAR_MID(); MM(0, 0, b0); PH_CLOSE();
    // ---- ph2: t0 q(0,1) ----
    RD_B(0, 1, b1);
    BAR_MID(); MM(0, 1, b1); PH_CLOSE();
    // ---- ph3: t0 q(1,0) ----
    RD_A(0, 1);
    STAGE_B(0, t0 + 2);
    BAR_MID(); MM(1, 0, b0); PH_CLOSE();
    // ---- ph4: t0 q(1,1) ----
    STAGE_A(0, t0 + 2); STAGE_B(1, t0 + 2);
    BAR_MID(); MM(1, 1, b1); PH_CLOSE_GATE();
    // ---- ph5: t1 q(0,0) ----
    RD_A(1, 0); RD_B(1, 0, b0);
    STAGE_A(1, t0 + 2);
    BAR_MID(); MM(0, 0, b0); PH_CLOSE();
    // ---- ph6: t1 q(0,1) ----
    RD_B(1, 1, b1);
    BAR_MID(); MM(0, 1, b1); PH_CLOSE();
    // ---- ph7: t1 q(1,0) ----
    RD_A(1, 1);
    STAGE_B(0, t0 + 3);
    BAR_MID(); MM(1, 0, b0); PH_CLOSE();
    // ---- ph8: t1 q(1,1) ----
    STAGE_A(0, t0 + 3); STAGE_B(1, t0 + 3);
    BAR_MID(); MM(1, 1, b1); PH_CLOSE_GATE();
  }

  // ---- epilogue ----
#pragma unroll
  for (int g = 0; g < 2; ++g)
#pragma unroll
    for (int mf = 0; mf < 4; ++mf)
#pragma unroll
      for (int ng = 0; ng < 2; ++ng)
#pragma unroll
        for (int nfi = 0; nfi < 2; ++nfi) {
          const f32x4 v = acc[g * 4 + mf][ng * 2 + nfi];
          const int row0 = m0 + wm * 128 + g * 64 + mf * 16 + hi * 4;
          const int col = n0 + wn * 64 + ng * 32 + nfi * 16 + lo;
          if (F32OUT) {
            const float bb = bias[col];
#pragma unroll
            for (int r = 0; r < 4; ++r)
              Cf[(size_t)(row0 + r) * N + col] = v[r] + bb;
          } else {
#pragma unroll
            for (int r = 0; r < 4; ++r)
              Cb[(size_t)(row0 + r) * N + col] = f2bf(v[r]);
          }
        }
#undef STAGE_A
#undef STAGE_B
#undef RD_A
#undef RD_B
#undef MM
#undef BAR_MID
#undef PH_CLOSE
#undef PH_CLOSE_GATE
}

// ---------------- VT build: vt[b*20+h][d=64][k=96] from kvc V columns ----------------
__global__ __launch_bounds__(256) void build_vt(const u16* __restrict__ kvc,
                                                u16* __restrict__ vt) {
  __shared__ u16 Ls[96][72];
  const int tid = threadIdx.x;
  const int h = blockIdx.x % 20, b = blockIdx.x / 20;
  for (int idx = tid; idx < 96 * 8; idx += 256) {
    const int row = idx >> 3, c8 = (idx & 7) << 3;
    uint4 val = make_uint4(0, 0, 0, 0);
    if (row < 77)
      val = *(const uint4*)(kvc + (size_t)(b * 77 + row) * 5120 + 1280 + h * 64 + c8);
    else if (row >= 80 && row < 84)
      val = *(const uint4*)(kvc + (size_t)(640 + b * 4 + row - 80) * 5120 + 3840 + h * 64 + c8);
    *(uint4*)&Ls[row][c8] = val;
  }
  __syncthreads();
  u16* dst = vt + (size_t)blockIdx.x * 64 * 96;
  for (int idx = tid; idx < 768; idx += 256) {
    const int d = idx / 12, c = (idx % 12) * 8;
    u16 tmp[8];
#pragma unroll
    for (int j = 0; j < 8; ++j) tmp[j] = Ls[c + j][d];
    *(uint4*)(dst + d * 96 + c) = *(const uint4*)tmp;
  }
}

// ---------------- attention v2: swapped-QK, zero-LDS, wave-independent ----------------
__global__ __launch_bounds__(256) void attn2(
    const u16* __restrict__ Q, const u16* __restrict__ kvc,
    const u16* __restrict__ vt, u16* __restrict__ O) {
  const int tid = threadIdx.x;
  const int w = tid >> 6, lane = tid & 63;
  const int l31 = lane & 31, hi5 = lane >> 5;
  const int bid = blockIdx.x;
  const int qc = bid & 31;
  const int h = (bid >> 5) % 20;
  const int b = bid / 640;
  const int q0 = qc * 128 + w * 32;
  const size_t qrow = (size_t)b * 4096 + q0 + l31;

  bf16x8 qf[4];
  const u16* qp = Q + qrow * 1280 + h * 64 + hi5 * 8;
#pragma unroll
  for (int dc = 0; dc < 4; ++dc) qf[dc] = *(const bf16x8*)(qp + dc * 16);

  f32x16 s[3];
#pragma unroll
  for (int kf = 0; kf < 3; ++kf)
#pragma unroll
    for (int r = 0; r < 16; ++r) s[kf][r] = 0.f;

#pragma unroll
  for (int kf = 0; kf < 3; ++kf) {
    const int key = kf * 32 + l31;
    const u16* kp;
    if (key < 77) kp = kvc + (size_t)(b * 77 + key) * 5120 + h * 64 + hi5 * 8;
    else if (key >= 80 && key < 84)
      kp = kvc + (size_t)(640 + b * 4 + key - 80) * 5120 + 2560 + h * 64 + hi5 * 8;
    else kp = kvc + h * 64 + hi5 * 8;  // masked later
    bf16x8 ka[4];
#pragma unroll
    for (int dc = 0; dc < 4; ++dc) ka[dc] = *(const bf16x8*)(kp + dc * 16);
#pragma unroll
    for (int dc = 0; dc < 4; ++dc) s[kf] = MFMA32(ka[dc], qf[dc], s[kf]);
  }

  float st = 0.f, si = 0.f;
#pragma unroll
  for (int kf = 0; kf < 3; ++kf)
#pragma unroll
    for (int r = 0; r < 16; ++r) {
      const int krem = (r & 3) + 8 * (r >> 2);
      const int k = kf * 32 + krem + 4 * hi5;
      const bool vtx = k < 77;
      const bool vip = (k >= 80) & (k < 84);
      const float e = (vtx | vip) ? __expf(s[kf][r] * 0.125f) : 0.f;
      s[kf][r] = e;
      st += vtx ? e : 0.f;
      si += vip ? e : 0.f;
    }
  st += __shfl_xor(st, 32);
  si += __shfl_xor(si, 32);
  const float rt = __fdividef(1.f, st);
  const float ri = __fdividef(1.f, si);
#pragma unroll
  for (int kf = 0; kf < 3; ++kf)
#pragma unroll
    for (int r = 0; r < 16; ++r) {
      const int krem = (r & 3) + 8 * (r >> 2);
      const int k = kf * 32 + krem + 4 * hi5;
      const bool vip = (k >= 80) & (k < 84);
      s[kf][r] *= vip ? ri : rt;
    }

  f32x16 acc[2];
#pragma unroll
  for (int nf = 0; nf < 2; ++nf)
#pragma unroll
    for (int r = 0; r < 16; ++r) acc[nf][r] = 0.f;

  const u16* vbase = vt + ((size_t)(b * 20 + h) * 64) * 96 + hi5 * 8;
#pragma unroll
  for (int ks = 0; ks < 6; ++ks) {
    const int kf = ks >> 1;
    const int rb = (ks & 1) * 8;
    const u32 lo01 = cvtpk(s[kf][rb + 0], s[kf][rb + 1]);
    const u32 lo23 = cvtpk(s[kf][rb + 2], s[kf][rb + 3]);
    const u32 hi01 = cvtpk(s[kf][rb + 4], s[kf][rb + 5]);
    const u32 hi23 = cvtpk(s[kf][rb + 6], s[kf][rb + 7]);
    const u32 plo01 = __shfl_xor(lo01, 32);
    const u32 plo23 = __shfl_xor(lo23, 32);
    const u32 phi01 = __shfl_xor(hi01, 32);
    const u32 phi23 = __shfl_xor(hi23, 32);
    union { u32 u[4]; bf16x8 v; } pu;
    pu.u[0] = hi5 ? phi01 : lo01;
    pu.u[1] = hi5 ? phi23 : lo23;
    pu.u[2] = hi5 ? hi01 : plo01;
    pu.u[3] = hi5 ? hi23 : plo23;
#pragma unroll
    for (int nf = 0; nf < 2; ++nf) {
      const bf16x8 vb = *(const bf16x8*)(vbase + (size_t)(nf * 32 + l31) * 96 + ks * 16);
      acc[nf] = MFMA32(pu.v, vb, acc[nf]);
    }
  }

#pragma unroll
  for (int nf = 0; nf < 2; ++nf)
#pragma unroll
    for (int r = 0; r < 16; ++r) {
      const int row = q0 + (r & 3) + 8 * (r >> 2) + 4 * hi5;
      O[((size_t)b * 4096 + row) * 1280 + h * 64 + nf * 32 + l31] = f2bf(acc[nf][r]);
    }
}

// ---------------- launch ----------------
extern "C" void kernel_launch(void* const* d_in, const int* in_sizes, int n_in,
                              void* d_out, int out_size, void* d_ws, size_t ws_size,
                              hipStream_t stream) {
  (void)in_sizes; (void)n_in; (void)out_size; (void)ws_size;
  const float* hs   = (const float*)d_in[0];
  const float* enc  = (const float*)d_in[1];
  const float* ip   = (const float*)d_in[2];
  const float* Wq   = (const float*)d_in[3];
  const float* Wk   = (const float*)d_in[4];
  const float* Wv   = (const float*)d_in[5];
  const float* Wkip = (const float*)d_in[6];
  const float* Wvip = (const float*)d_in[7];
  const float* Wo   = (const float*)d_in[8];
  const float* bo   = (const float*)d_in[9];
  float* out = (float*)d_out;

  // d_out (167.8 MB) as scratch: q_bf first half, hs_bf second half
  // (both dead before the final f32 output write).
  u16* q_bf  = (u16*)d_out;
  u16* hs_bf = (u16*)d_out + 41943040;

  // ws layout. wq_t/kvw/a_all overlap the attn region (dead before attn2).
  char* ws = (char*)d_ws;
  u16* kvc   = (u16*)(ws);                         // 15,728,640 B  [768][5120]
  u16* wo_t  = (u16*)(ws + 15728640);              //  3,276,800 B
  u16* vt    = (u16*)(ws + 19005440);              //  1,966,080 B  [160][64][96]
  u16* attn  = (u16*)(ws + 20971520);              // 83,886,080 B
  u16* wq_t  = attn;                               //  3,276,800 B (overlap)
  u16* kvw   = (u16*)(ws + 20971520 + 3276800);    // 20,971,520 B (overlap) [5120][2048]
  u16* a_all = (u16*)(ws + 20971520 + 24248320);   //  3,145,728 B (overlap) [768][2048]

  f32_to_bf16_vec<<<40960, 256, 0, stream>>>(hs, hs_bf, 10485760);
  build_a_all<<<1536, 256, 0, stream>>>(enc, ip, a_all);

  dim3 tb(32, 8);
  transpose_w4<<<dim3(40, 64, 4), tb, 0, stream>>>(Wk, Wv, Wkip, Wvip, kvw);
  transpose_w2<<<dim3(40, 40, 2), tb, 0, stream>>>(Wq, Wo, wq_t, wo_t);

  // Q-proj
  gemm8p<0><<<640, 512, 0, stream>>>(hs_bf, wq_t, q_bf, nullptr, nullptr, 32768, 1280, 1280);
  // fused K/V projections
  gemm8p<0><<<60, 512, 0, stream>>>(a_all, kvw, kvc, nullptr, nullptr, 768, 5120, 2048);

  build_vt<<<160, 256, 0, stream>>>(kvc, vt);

  attn2<<<5120, 256, 0, stream>>>(q_bf, kvc, vt, attn);

  // O-proj + bias (f32 out)
  gemm8p<1><<<640, 512, 0, stream>>>(attn, wo_t, nullptr, out, bo, 32768, 1280, 1280);
}

// Round 6
// 408.207 us; speedup vs baseline: 1.0888x; 1.0312x over previous
//
#include <hip/hip_runtime.h>

using u16 = unsigned short;
using u32 = unsigned int;
typedef __bf16 bf16x8 __attribute__((ext_vector_type(8)));
typedef float f32x4 __attribute__((ext_vector_type(4)));
typedef float f32x16 __attribute__((ext_vector_type(16)));

__device__ __forceinline__ u16 f2bf(float f) {
  u32 u = __float_as_uint(f);
  u += 0x7FFFu + ((u >> 16) & 1u);
  return (u16)(u >> 16);
}

__device__ __forceinline__ u32 cvtpk(float a, float b) {
  u32 r;
  asm("v_cvt_pk_bf16_f32 %0, %1, %2" : "=v"(r) : "v"(a), "v"(b));
  return r;
}

__device__ __forceinline__ void gload16(const u16* g, u16* l) {
  __builtin_amdgcn_global_load_lds((const __attribute__((address_space(1))) void*)g,
                                   (__attribute__((address_space(3))) void*)l, 16, 0, 0);
}

// ---------------- conversion kernels ----------------
__global__ void f32_to_bf16_vec(const float* __restrict__ in, u16* __restrict__ out, long n4) {
  const long i = (long)blockIdx.x * 256 + threadIdx.x;
  if (i >= n4) return;
  const float4 v = ((const float4*)in)[i];
  ushort4 o;
  o.x = f2bf(v.x); o.y = f2bf(v.y); o.z = f2bf(v.z); o.w = f2bf(v.w);
  ((ushort4*)out)[i] = o;
}

// A_all [768][2048]: rows 0..615 = enc, 640..671 = ip, rest zero.
__global__ void build_a_all(const float* __restrict__ enc, const float* __restrict__ ip,
                            u16* __restrict__ out) {
  const int i = blockIdx.x * 256 + threadIdx.x;
  const int row = i >> 9;
  const int c4 = i & 511;
  ushort4 o = {0, 0, 0, 0};
  const float4* src = nullptr;
  if (row < 616) src = (const float4*)enc + (size_t)row * 512 + c4;
  else if (row >= 640 && row < 672) src = (const float4*)ip + (size_t)(row - 640) * 512 + c4;
  if (src) {
    const float4 v = *src;
    o.x = f2bf(v.x); o.y = f2bf(v.y); o.z = f2bf(v.z); o.w = f2bf(v.w);
  }
  ((ushort4*)out)[i] = o;
}

// 4 x (f32 [2048][1280] -> bf16 [1280][2048]), z selects weight
__global__ void transpose_w4(const float* __restrict__ s0, const float* __restrict__ s1,
                             const float* __restrict__ s2, const float* __restrict__ s3,
                             u16* __restrict__ dst) {
  __shared__ float tile[32][33];
  const int z = blockIdx.z;
  const float* in = (z == 0) ? s0 : (z == 1) ? s1 : (z == 2) ? s2 : s3;
  u16* out = dst + (size_t)z * 1280 * 2048;
  const int K = 2048, N = 1280;
  const int n0 = blockIdx.x << 5, k0 = blockIdx.y << 5;
  const int x = threadIdx.x, y = threadIdx.y;  // (32, 8)
#pragma unroll
  for (int i = 0; i < 32; i += 8)
    tile[y + i][x] = in[(size_t)(k0 + y + i) * N + n0 + x];
  __syncthreads();
#pragma unroll
  for (int i = 0; i < 32; i += 8)
    out[(size_t)(n0 + y + i) * K + k0 + x] = f2bf(tile[x][y + i]);
}

// 2 x (f32 [1280][1280] -> bf16 [1280][1280]), z selects
__global__ void transpose_w2(const float* __restrict__ s0, const float* __restrict__ s1,
                             u16* __restrict__ d0, u16* __restrict__ d1) {
  __shared__ float tile[32][33];
  const int z = blockIdx.z;
  const float* in = z ? s1 : s0;
  u16* out = z ? d1 : d0;
  const int K = 1280, N = 1280;
  const int n0 = blockIdx.x << 5, k0 = blockIdx.y << 5;
  const int x = threadIdx.x, y = threadIdx.y;
#pragma unroll
  for (int i = 0; i < 32; i += 8)
    tile[y + i][x] = in[(size_t)(k0 + y + i) * N + n0 + x];
  __syncthreads();
#pragma unroll
  for (int i = 0; i < 32; i += 8)
    out[(size_t)(n0 + y + i) * K + k0 + x] = f2bf(tile[x][y + i]);
}

// ---------------- 256x256 4-phase pipelined GEMM (r3 measured-best) ----------------
#define MFMA16(a, b, c) __builtin_amdgcn_mfma_f32_16x16x32_bf16(a, b, c, 0, 0, 0)
#define MFMA32(a, b, c) __builtin_amdgcn_mfma_f32_32x32x16_bf16(a, b, c, 0, 0, 0)

template <int F32OUT>
__global__ __launch_bounds__(512, 2) void gemm256(
    const u16* __restrict__ A, const u16* __restrict__ Bt,
    u16* __restrict__ Cb, float* __restrict__ Cf, const float* __restrict__ bias,
    int M, int N, int K) {
  __shared__ __align__(16) u16 smem[65536];
  u16* As = smem;
  u16* Bs = smem + 32768;

  const int tid = threadIdx.x;
  const int w = tid >> 6, lane = tid & 63;
  const int lo = lane & 15, hi = lane >> 4;
  const int wm = w >> 2, wn = w & 3;

  const int nbn = N >> 8;
  int wg = blockIdx.x;
  {  // bijective XCD swizzle (m204)
    const int nwg = gridDim.x;
    const int q = nwg >> 3, r = nwg & 7;
    const int xcd = wg & 7, l = wg >> 3;
    wg = (xcd < r ? xcd * (q + 1) : r * (q + 1) + (xcd - r) * q) + l;
  }
  const int bm = wg / nbn, bn = wg % nbn;
  const int m0 = bm << 8, n0 = bn << 8;
  const int NT = K >> 6;

  const int sr = lane >> 3;
  const int sc8 = ((lane & 7) ^ sr) << 3;
  const u16* pA[2];
  const u16* pB[2];
#pragma unroll
  for (int i = 0; i < 2; ++i) {
    const int rr = (i * 8 + w) * 8 + sr;
    pA[i] = A + (size_t)(m0 + rr) * K + sc8;
    pB[i] = Bt + (size_t)(n0 + rr) * K + sc8;
  }
  const int ch0 = w * 512, ch1 = (8 + w) * 512;

#define STAGE_A(h, tt)                                                     \
  {                                                                        \
    const int ttc = ((tt) < NT) ? (tt) : (NT - 1);                         \
    u16* d = As + ((((tt)&1) * 2 + (h)) << 13);                            \
    const size_t off = (size_t)(h)*128 * K + (size_t)ttc * 64;             \
    gload16(pA[0] + off, d + ch0);                                         \
    gload16(pA[1] + off, d + ch1);                                         \
  }
#define STAGE_B(h, tt)                                                     \
  {                                                                        \
    const int ttc = ((tt) < NT) ? (tt) : (NT - 1);                         \
    u16* d = Bs + ((((tt)&1) * 2 + (h)) << 13);                            \
    const size_t off = (size_t)(h)*128 * K + (size_t)ttc * 64;             \
    gload16(pB[0] + off, d + ch0);                                         \
    gload16(pB[1] + off, d + ch1);                                         \
  }

  const int low0 = (lo << 7) | ((hi ^ (lo & 7)) << 4);
  const int low1 = (lo << 7) | (((4 | hi) ^ (lo & 7)) << 4);

  f32x4 acc[8][4];
#pragma unroll
  for (int i = 0; i < 8; ++i)
#pragma unroll
    for (int j = 0; j < 4; ++j) acc[i][j] = (f32x4){0.f, 0.f, 0.f, 0.f};

  STAGE_B(0, 0); STAGE_B(1, 0);
  STAGE_A(0, 0); STAGE_A(1, 0);
  STAGE_B(0, 1); STAGE_B(1, 1);

  const char* aSm = (const char*)As;
  const char* bSm = (const char*)Bs;

  for (int t = 0; t < NT; ++t) {
    const int p = t & 1;
    const int aBase = (p * 2 + wm) << 14;
    const int bBase = ((p * 2 + (wn >> 1)) << 14) + ((wn & 1) << 13);

    asm volatile("s_waitcnt vmcnt(4)" ::: "memory");
    asm volatile("s_barrier" ::: "memory");

    bf16x8 a0[4][2], a1[4][2], b0[2][2], b1[2][2];
    // ---- ph0 ----
#pragma unroll
    for (int mf = 0; mf < 4; ++mf) {
      a0[mf][0] = *(const bf16x8*)(aSm + aBase + (mf << 11) + low0);
      a0[mf][1] = *(const bf16x8*)(aSm + aBase + (mf << 11) + low1);
    }
#pragma unroll
    for (int nf = 0; nf < 2; ++nf) {
      b0[nf][0] = *(const bf16x8*)(bSm + bBase + (nf << 11) + low0);
      b0[nf][1] = *(const bf16x8*)(bSm + bBase + (nf << 11) + low1);
    }
    STAGE_A(0, t + 1);
    __builtin_amdgcn_s_setprio(1);
#pragma unroll
    for (int mf = 0; mf < 4; ++mf)
#pragma unroll
      for (int nf = 0; nf < 2; ++nf) {
        acc[mf][nf] = MFMA16(a0[mf][0], b0[nf][0], acc[mf][nf]);
        acc[mf][nf] = MFMA16(a0[mf][1], b0[nf][1], acc[mf][nf]);
      }
    __builtin_amdgcn_s_setprio(0);
    asm volatile("s_barrier" ::: "memory");

    // ---- ph1 ----
#pragma unroll
    for (int nf = 0; nf < 2; ++nf) {
      b1[nf][0] = *(const bf16x8*)(bSm + bBase + (1 << 12) + (nf << 11) + low0);
      b1[nf][1] = *(const bf16x8*)(bSm + bBase + (1 << 12) + (nf << 11) + low1);
    }
    STAGE_A(1, t + 1);
    __builtin_amdgcn_s_setprio(1);
#pragma unroll
    for (int mf = 0; mf < 4; ++mf)
#pragma unroll
      for (int nf = 0; nf < 2; ++nf) {
        acc[mf][2 + nf] = MFMA16(a0[mf][0], b1[nf][0], acc[mf][2 + nf]);
        acc[mf][2 + nf] = MFMA16(a0[mf][1], b1[nf][1], acc[mf][2 + nf]);
      }
    __builtin_amdgcn_s_setprio(0);
    asm volatile("s_barrier" ::: "memory");

    // ---- ph2 ----
#pragma unroll
    for (int mf = 0; mf < 4; ++mf) {
      a1[mf][0] = *(const bf16x8*)(aSm + aBase + (1 << 13) + (mf << 11) + low0);
      a1[mf][1] = *(const bf16x8*)(aSm + aBase + (1 << 13) + (mf << 11) + low1);
    }
    STAGE_B(0, t + 2);
    __builtin_amdgcn_s_setprio(1);
#pragma unroll
    for (int mf = 0; mf < 4; ++mf)
#pragma unroll
      for (int nf = 0; nf < 2; ++nf) {
        acc[4 + mf][nf] = MFMA16(a1[mf][0], b0[nf][0], acc[4 + mf][nf]);
        acc[4 + mf][nf] = MFMA16(a1[mf][1], b0[nf][1], acc[4 + mf][nf]);
      }
    __builtin_amdgcn_s_setprio(0);
    asm volatile("s_barrier" ::: "memory");

    // ---- ph3 ----
    STAGE_B(1, t + 2);
    __builtin_amdgcn_s_setprio(1);
#pragma unroll
    for (int mf = 0; mf < 4; ++mf)
#pragma unroll
      for (int nf = 0; nf < 2; ++nf) {
        acc[4 + mf][2 + nf] = MFMA16(a1[mf][0], b1[nf][0], acc[4 + mf][2 + nf]);
        acc[4 + mf][2 + nf] = MFMA16(a1[mf][1], b1[nf][1], acc[4 + mf][2 + nf]);
      }
    __builtin_amdgcn_s_setprio(0);
  }

  // ---- epilogue ----
#pragma unroll
  for (int g = 0; g < 2; ++g)
#pragma unroll
    for (int mf = 0; mf < 4; ++mf)
#pragma unroll
      for (int ng = 0; ng < 2; ++ng)
#pragma unroll
        for (int nfi = 0; nfi < 2; ++nfi) {
          const f32x4 v = acc[g * 4 + mf][ng * 2 + nfi];
          const int row0 = m0 + wm * 128 + g * 64 + mf * 16 + hi * 4;
          const int col = n0 + wn * 64 + ng * 32 + nfi * 16 + lo;
          if (F32OUT) {
            const float bb = bias[col];
#pragma unroll
            for (int r = 0; r < 4; ++r)
              Cf[(size_t)(row0 + r) * N + col] = v[r] + bb;
          } else {
#pragma unroll
            for (int r = 0; r < 4; ++r)
              Cb[(size_t)(row0 + r) * N + col] = f2bf(v[r]);
          }
        }
#undef STAGE_A
#undef STAGE_B
}

// ---------------- VT build: vt[b*20+h][d=64][k=96] from kvc V columns ----------------
__global__ __launch_bounds__(256) void build_vt(const u16* __restrict__ kvc,
                                                u16* __restrict__ vt) {
  __shared__ u16 Ls[96][72];
  const int tid = threadIdx.x;
  const int h = blockIdx.x % 20, b = blockIdx.x / 20;
  for (int idx = tid; idx < 96 * 8; idx += 256) {
    const int row = idx >> 3, c8 = (idx & 7) << 3;
    uint4 val = make_uint4(0, 0, 0, 0);
    if (row < 77)
      val = *(const uint4*)(kvc + (size_t)(b * 77 + row) * 5120 + 1280 + h * 64 + c8);
    else if (row >= 80 && row < 84)
      val = *(const uint4*)(kvc + (size_t)(640 + b * 4 + row - 80) * 5120 + 3840 + h * 64 + c8);
    *(uint4*)&Ls[row][c8] = val;
  }
  __syncthreads();
  u16* dst = vt + (size_t)blockIdx.x * 64 * 96;
  for (int idx = tid; idx < 768; idx += 256) {
    const int d = idx / 12, c = (idx % 12) * 8;
    u16 tmp[8];
#pragma unroll
    for (int j = 0; j < 8; ++j) tmp[j] = Ls[c + j][d];
    *(uint4*)(dst + d * 96 + c) = *(const uint4*)tmp;
  }
}

// ---------------- attention v3: swapped-QK, zero-LDS, NQ=2 (64 q/wave) ----------------
// Per wave: 64 queries (2 groups of 32) x 96 keys x d=64; K loads shared
// across groups; PV sequential per group to cap register pressure.
__global__ __launch_bounds__(256) void attn3(
    const u16* __restrict__ Q, const u16* __restrict__ kvc,
    const u16* __restrict__ vt, u16* __restrict__ O) {
  const int tid = threadIdx.x;
  const int w = tid >> 6, lane = tid & 63;
  const int l31 = lane & 31, hi5 = lane >> 5;
  const int bid = blockIdx.x;
  const int qc = bid & 15;          // 16 chunks of 256 queries
  const int h = (bid >> 4) % 20;
  const int b = bid / 320;
  const int q0 = qc * 256 + w * 64; // wave covers q0..q0+63
  const size_t qbase = (size_t)b * 4096 + q0;

  bf16x8 qf0[4], qf1[4];
  {
    const u16* qp0 = Q + (qbase + l31) * 1280 + h * 64 + hi5 * 8;
    const u16* qp1 = Q + (qbase + 32 + l31) * 1280 + h * 64 + hi5 * 8;
#pragma unroll
    for (int dc = 0; dc < 4; ++dc) {
      qf0[dc] = *(const bf16x8*)(qp0 + dc * 16);
      qf1[dc] = *(const bf16x8*)(qp1 + dc * 16);
    }
  }

  f32x16 s0[3], s1[3];
#pragma unroll
  for (int kf = 0; kf < 3; ++kf)
#pragma unroll
    for (int r = 0; r < 16; ++r) { s0[kf][r] = 0.f; s1[kf][r] = 0.f; }

  // QK^T (swapped): A = K rows (shared), B = Q rows (per group)
#pragma unroll
  for (int kf = 0; kf < 3; ++kf) {
    const int key = kf * 32 + l31;
    const u16* kp;
    if (key < 77) kp = kvc + (size_t)(b * 77 + key) * 5120 + h * 64 + hi5 * 8;
    else if (key >= 80 && key < 84)
      kp = kvc + (size_t)(640 + b * 4 + key - 80) * 5120 + 2560 + h * 64 + hi5 * 8;
    else kp = kvc + h * 64 + hi5 * 8;  // masked later
    bf16x8 ka[4];
#pragma unroll
    for (int dc = 0; dc < 4; ++dc) ka[dc] = *(const bf16x8*)(kp + dc * 16);
#pragma unroll
    for (int dc = 0; dc < 4; ++dc) {
      s0[kf] = MFMA32(ka[dc], qf0[dc], s0[kf]);
      s1[kf] = MFMA32(ka[dc], qf1[dc], s1[kf]);
    }
  }

  // in-register masked softmax, both groups
  float st0 = 0.f, si0 = 0.f, st1 = 0.f, si1 = 0.f;
#pragma unroll
  for (int kf = 0; kf < 3; ++kf)
#pragma unroll
    for (int r = 0; r < 16; ++r) {
      const int krem = (r & 3) + 8 * (r >> 2);
      const int k = kf * 32 + krem + 4 * hi5;
      const bool vtx = k < 77;
      const bool vip = (k >= 80) & (k < 84);
      const float e0 = (vtx | vip) ? __expf(s0[kf][r] * 0.125f) : 0.f;
      const float e1 = (vtx | vip) ? __expf(s1[kf][r] * 0.125f) : 0.f;
      s0[kf][r] = e0; s1[kf][r] = e1;
      st0 += vtx ? e0 : 0.f; si0 += vip ? e0 : 0.f;
      st1 += vtx ? e1 : 0.f; si1 += vip ? e1 : 0.f;
    }
  st0 += __shfl_xor(st0, 32); si0 += __shfl_xor(si0, 32);
  st1 += __shfl_xor(st1, 32); si1 += __shfl_xor(si1, 32);
  const float rt0 = __fdividef(1.f, st0), ri0 = __fdividef(1.f, si0);
  const float rt1 = __fdividef(1.f, st1), ri1 = __fdividef(1.f, si1);
#pragma unroll
  for (int kf = 0; kf < 3; ++kf)
#pragma unroll
    for (int r = 0; r < 16; ++r) {
      const int krem = (r & 3) + 8 * (r >> 2);
      const int k = kf * 32 + krem + 4 * hi5;
      const bool vip = (k >= 80) & (k < 84);
      s0[kf][r] *= vip ? ri0 : rt0;
      s1[kf][r] *= vip ? ri1 : rt1;
    }

  const u16* vbase = vt + ((size_t)(b * 20 + h) * 64) * 96 + hi5 * 8;

  // PV per group (sequential to cap registers; vb reloads hit L1)
#define PV_STORE(sA, qoff)                                                  \
  {                                                                         \
    f32x16 acc[2];                                                          \
    _Pragma("unroll") for (int nf = 0; nf < 2; ++nf)                        \
    _Pragma("unroll") for (int r = 0; r < 16; ++r) acc[nf][r] = 0.f;        \
    _Pragma("unroll") for (int ks = 0; ks < 6; ++ks) {                      \
      const int kf = ks >> 1;                                               \
      const int rb = (ks & 1) * 8;                                          \
      const u32 lo01 = cvtpk(sA[kf][rb + 0], sA[kf][rb + 1]);               \
      const u32 lo23 = cvtpk(sA[kf][rb + 2], sA[kf][rb + 3]);               \
      const u32 hi01 = cvtpk(sA[kf][rb + 4], sA[kf][rb + 5]);               \
      const u32 hi23 = cvtpk(sA[kf][rb + 6], sA[kf][rb + 7]);               \
      const u32 plo01 = __shfl_xor(lo01, 32);                               \
      const u32 plo23 = __shfl_xor(lo23, 32);                               \
      const u32 phi01 = __shfl_xor(hi01, 32);                               \
      const u32 phi23 = __shfl_xor(hi23, 32);                               \
      union { u32 u[4]; bf16x8 v; } pu;                                     \
      pu.u[0] = hi5 ? phi01 : lo01;                                         \
      pu.u[1] = hi5 ? phi23 : lo23;                                         \
      pu.u[2] = hi5 ? hi01 : plo01;                                         \
      pu.u[3] = hi5 ? hi23 : plo23;                                         \
      _Pragma("unroll") for (int nf = 0; nf < 2; ++nf) {                    \
        const bf16x8 vb =                                                   \
            *(const bf16x8*)(vbase + (size_t)(nf * 32 + l31) * 96 + ks * 16);\
        acc[nf] = MFMA32(pu.v, vb, acc[nf]);                                \
      }                                                                     \
    }                                                                       \
    _Pragma("unroll") for (int nf = 0; nf < 2; ++nf)                        \
    _Pragma("unroll") for (int r = 0; r < 16; ++r) {                        \
      const int row = q0 + (qoff) + (r & 3) + 8 * (r >> 2) + 4 * hi5;       \
      O[((size_t)b * 4096 + row) * 1280 + h * 64 + nf * 32 + l31] =         \
          f2bf(acc[nf][r]);                                                 \
    }                                                                       \
  }

  PV_STORE(s0, 0)
  PV_STORE(s1, 32)
#undef PV_STORE
}

// ---------------- launch ----------------
extern "C" void kernel_launch(void* const* d_in, const int* in_sizes, int n_in,
                              void* d_out, int out_size, void* d_ws, size_t ws_size,
                              hipStream_t stream) {
  (void)in_sizes; (void)n_in; (void)out_size; (void)ws_size;
  const float* hs   = (const float*)d_in[0];
  const float* enc  = (const float*)d_in[1];
  const float* ip   = (const float*)d_in[2];
  const float* Wq   = (const float*)d_in[3];
  const float* Wk   = (const float*)d_in[4];
  const float* Wv   = (const float*)d_in[5];
  const float* Wkip = (const float*)d_in[6];
  const float* Wvip = (const float*)d_in[7];
  const float* Wo   = (const float*)d_in[8];
  const float* bo   = (const float*)d_in[9];
  float* out = (float*)d_out;

  // d_out (167.8 MB) as scratch: q_bf first half, hs_bf second half
  // (both dead before the final f32 output write).
  u16* q_bf  = (u16*)d_out;
  u16* hs_bf = (u16*)d_out + 41943040;

  // ws layout. wq_t/kvw/a_all overlap the attn region (dead before attn3).
  char* ws = (char*)d_ws;
  u16* kvc   = (u16*)(ws);                         // 15,728,640 B  [768][5120]
  u16* wo_t  = (u16*)(ws + 15728640);              //  3,276,800 B
  u16* vt    = (u16*)(ws + 19005440);              //  1,966,080 B  [160][64][96]
  u16* attn  = (u16*)(ws + 20971520);               // 83,886,080 B
  u16* wq_t  = attn;                                //  3,276,800 B (overlap)
  u16* kvw   = (u16*)(ws + 20971520 + 3276800);     // 20,971,520 B (overlap) [5120][2048]
  u16* a_all = (u16*)(ws + 20971520 + 24248320);    //  3,145,728 B (overlap) [768][2048]

  f32_to_bf16_vec<<<40960, 256, 0, stream>>>(hs, hs_bf, 10485760);
  build_a_all<<<1536, 256, 0, stream>>>(enc, ip, a_all);

  dim3 tb(32, 8);
  transpose_w4<<<dim3(40, 64, 4), tb, 0, stream>>>(Wk, Wv, Wkip, Wvip, kvw);
  transpose_w2<<<dim3(40, 40, 2), tb, 0, stream>>>(Wq, Wo, wq_t, wo_t);

  // Q-proj
  gemm256<0><<<640, 512, 0, stream>>>(hs_bf, wq_t, q_bf, nullptr, nullptr, 32768, 1280, 1280);
  // fused K/V projections
  gemm256<0><<<60, 512, 0, stream>>>(a_all, kvw, kvc, nullptr, nullptr, 768, 5120, 2048);

  build_vt<<<160, 256, 0, stream>>>(kvc, vt);

  attn3<<<2560, 256, 0, stream>>>(q_bf, kvc, vt, attn);

  // O-proj + bias (f32 out)
  gemm256<1><<<640, 512, 0, stream>>>(attn, wo_t, nullptr, out, bo, 32768, 1280, 1280);
}

// Round 7
// 373.413 us; speedup vs baseline: 1.1902x; 1.0932x over previous
//
#include <hip/hip_runtime.h>

using u16 = unsigned short;
using u32 = unsigned int;
typedef __bf16 bf16x8 __attribute__((ext_vector_type(8)));
typedef float f32x4 __attribute__((ext_vector_type(4)));
typedef float f32x16 __attribute__((ext_vector_type(16)));

__device__ __forceinline__ u16 f2bf(float f) {
  u32 u = __float_as_uint(f);
  u += 0x7FFFu + ((u >> 16) & 1u);
  return (u16)(u >> 16);
}

__device__ __forceinline__ u32 cvtpk(float a, float b) {
  u32 r;
  asm("v_cvt_pk_bf16_f32 %0, %1, %2" : "=v"(r) : "v"(a), "v"(b));
  return r;
}

__device__ __forceinline__ void gload16(const u16* g, u16* l) {
  __builtin_amdgcn_global_load_lds((const __attribute__((address_space(1))) void*)g,
                                   (__attribute__((address_space(3))) void*)l, 16, 0, 0);
}

// ---------------- conversion kernels ----------------
__global__ void f32_to_bf16_vec(const float* __restrict__ in, u16* __restrict__ out, long n4) {
  const long i = (long)blockIdx.x * 256 + threadIdx.x;
  if (i >= n4) return;
  const float4 v = ((const float4*)in)[i];
  ushort4 o;
  o.x = f2bf(v.x); o.y = f2bf(v.y); o.z = f2bf(v.z); o.w = f2bf(v.w);
  ((ushort4*)out)[i] = o;
}

// A_all [768][2048]: rows 0..615 = enc, 640..671 = ip, rest zero.
__global__ void build_a_all(const float* __restrict__ enc, const float* __restrict__ ip,
                            u16* __restrict__ out) {
  const int i = blockIdx.x * 256 + threadIdx.x;
  const int row = i >> 9;
  const int c4 = i & 511;
  ushort4 o = {0, 0, 0, 0};
  const float4* src = nullptr;
  if (row < 616) src = (const float4*)enc + (size_t)row * 512 + c4;
  else if (row >= 640 && row < 672) src = (const float4*)ip + (size_t)(row - 640) * 512 + c4;
  if (src) {
    const float4 v = *src;
    o.x = f2bf(v.x); o.y = f2bf(v.y); o.z = f2bf(v.z); o.w = f2bf(v.w);
  }
  ((ushort4*)out)[i] = o;
}

// 4 x (f32 [2048][1280] -> bf16 [1280][2048]), z selects weight
__global__ void transpose_w4(const float* __restrict__ s0, const float* __restrict__ s1,
                             const float* __restrict__ s2, const float* __restrict__ s3,
                             u16* __restrict__ dst) {
  __shared__ float tile[32][33];
  const int z = blockIdx.z;
  const float* in = (z == 0) ? s0 : (z == 1) ? s1 : (z == 2) ? s2 : s3;
  u16* out = dst + (size_t)z * 1280 * 2048;
  const int K = 2048, N = 1280;
  const int n0 = blockIdx.x << 5, k0 = blockIdx.y << 5;
  const int x = threadIdx.x, y = threadIdx.y;  // (32, 8)
#pragma unroll
  for (int i = 0; i < 32; i += 8)
    tile[y + i][x] = in[(size_t)(k0 + y + i) * N + n0 + x];
  __syncthreads();
#pragma unroll
  for (int i = 0; i < 32; i += 8)
    out[(size_t)(n0 + y + i) * K + k0 + x] = f2bf(tile[x][y + i]);
}

// 2 x (f32 [1280][1280] -> bf16 [1280][1280]), z selects
__global__ void transpose_w2(const float* __restrict__ s0, const float* __restrict__ s1,
                             u16* __restrict__ d0, u16* __restrict__ d1) {
  __shared__ float tile[32][33];
  const int z = blockIdx.z;
  const float* in = z ? s1 : s0;
  u16* out = z ? d1 : d0;
  const int K = 1280, N = 1280;
  const int n0 = blockIdx.x << 5, k0 = blockIdx.y << 5;
  const int x = threadIdx.x, y = threadIdx.y;
#pragma unroll
  for (int i = 0; i < 32; i += 8)
    tile[y + i][x] = in[(size_t)(k0 + y + i) * N + n0 + x];
  __syncthreads();
#pragma unroll
  for (int i = 0; i < 32; i += 8)
    out[(size_t)(n0 + y + i) * K + k0 + x] = f2bf(tile[x][y + i]);
}

// ---------------- 256x256 4-phase pipelined GEMM ----------------
// MODE 0: C -> bf16.  MODE 1: C -> f32 + bias.  MODE 2: fused attention
// epilogue (N must be 1280; wave (wm,wn) owns 128 queries x head 4*bn+wn).
#define MFMA16(a, b, c) __builtin_amdgcn_mfma_f32_16x16x32_bf16(a, b, c, 0, 0, 0)
#define MFMA32(a, b, c) __builtin_amdgcn_mfma_f32_32x32x16_bf16(a, b, c, 0, 0, 0)

template <int MODE>
__global__ __launch_bounds__(512, 2) void gemm256(
    const u16* __restrict__ A, const u16* __restrict__ Bt,
    u16* __restrict__ Cb, float* __restrict__ Cf, const float* __restrict__ bias,
    const u16* __restrict__ kvcP, const u16* __restrict__ vtP,
    int M, int N, int K) {
  // 135168 B: staging view = As(64K) + Bs(64K); attn view = 8 x 16896 B Q-chunks
  __shared__ __align__(16) u16 smem[67584];
  u16* As = smem;
  u16* Bs = smem + 32768;

  const int tid = threadIdx.x;
  const int w = tid >> 6, lane = tid & 63;
  const int lo = lane & 15, hi = lane >> 4;
  const int wm = w >> 2, wn = w & 3;

  const int nbn = N >> 8;
  int wg = blockIdx.x;
  {  // bijective XCD swizzle (m204)
    const int nwg = gridDim.x;
    const int q = nwg >> 3, r = nwg & 7;
    const int xcd = wg & 7, l = wg >> 3;
    wg = (xcd < r ? xcd * (q + 1) : r * (q + 1) + (xcd - r) * q) + l;
  }
  const int bm = wg / nbn, bn = wg % nbn;
  const int m0 = bm << 8, n0 = bn << 8;
  const int NT = K >> 6;

  const int sr = lane >> 3;
  const int sc8 = ((lane & 7) ^ sr) << 3;
  const u16* pA[2];
  const u16* pB[2];
#pragma unroll
  for (int i = 0; i < 2; ++i) {
    const int rr = (i * 8 + w) * 8 + sr;
    pA[i] = A + (size_t)(m0 + rr) * K + sc8;
    pB[i] = Bt + (size_t)(n0 + rr) * K + sc8;
  }
  const int ch0 = w * 512, ch1 = (8 + w) * 512;

#define STAGE_A(h, tt)                                                     \
  {                                                                        \
    const int ttc = ((tt) < NT) ? (tt) : (NT - 1);                         \
    u16* d = As + ((((tt)&1) * 2 + (h)) << 13);                            \
    const size_t off = (size_t)(h)*128 * K + (size_t)ttc * 64;             \
    gload16(pA[0] + off, d + ch0);                                         \
    gload16(pA[1] + off, d + ch1);                                         \
  }
#define STAGE_B(h, tt)                                                     \
  {                                                                        \
    const int ttc = ((tt) < NT) ? (tt) : (NT - 1);                         \
    u16* d = Bs + ((((tt)&1) * 2 + (h)) << 13);                            \
    const size_t off = (size_t)(h)*128 * K + (size_t)ttc * 64;             \
    gload16(pB[0] + off, d + ch0);                                         \
    gload16(pB[1] + off, d + ch1);                                         \
  }

  const int low0 = (lo << 7) | ((hi ^ (lo & 7)) << 4);
  const int low1 = (lo << 7) | (((4 | hi) ^ (lo & 7)) << 4);

  f32x4 acc[8][4];
#pragma unroll
  for (int i = 0; i < 8; ++i)
#pragma unroll
    for (int j = 0; j < 4; ++j) acc[i][j] = (f32x4){0.f, 0.f, 0.f, 0.f};

  STAGE_B(0, 0); STAGE_B(1, 0);
  STAGE_A(0, 0); STAGE_A(1, 0);
  STAGE_B(0, 1); STAGE_B(1, 1);

  const char* aSm = (const char*)As;
  const char* bSm = (const char*)Bs;

  for (int t = 0; t < NT; ++t) {
    const int p = t & 1;
    const int aBase = (p * 2 + wm) << 14;
    const int bBase = ((p * 2 + (wn >> 1)) << 14) + ((wn & 1) << 13);

    asm volatile("s_waitcnt vmcnt(4)" ::: "memory");
    asm volatile("s_barrier" ::: "memory");

    bf16x8 a0[4][2], a1[4][2], b0[2][2], b1[2][2];
    // ---- ph0 ----
#pragma unroll
    for (int mf = 0; mf < 4; ++mf) {
      a0[mf][0] = *(const bf16x8*)(aSm + aBase + (mf << 11) + low0);
      a0[mf][1] = *(const bf16x8*)(aSm + aBase + (mf << 11) + low1);
    }
#pragma unroll
    for (int nf = 0; nf < 2; ++nf) {
      b0[nf][0] = *(const bf16x8*)(bSm + bBase + (nf << 11) + low0);
      b0[nf][1] = *(const bf16x8*)(bSm + bBase + (nf << 11) + low1);
    }
    STAGE_A(0, t + 1);
    __builtin_amdgcn_s_setprio(1);
#pragma unroll
    for (int mf = 0; mf < 4; ++mf)
#pragma unroll
      for (int nf = 0; nf < 2; ++nf) {
        acc[mf][nf] = MFMA16(a0[mf][0], b0[nf][0], acc[mf][nf]);
        acc[mf][nf] = MFMA16(a0[mf][1], b0[nf][1], acc[mf][nf]);
      }
    __builtin_amdgcn_s_setprio(0);
    asm volatile("s_barrier" ::: "memory");

    // ---- ph1 ----
#pragma unroll
    for (int nf = 0; nf < 2; ++nf) {
      b1[nf][0] = *(const bf16x8*)(bSm + bBase + (1 << 12) + (nf << 11) + low0);
      b1[nf][1] = *(const bf16x8*)(bSm + bBase + (1 << 12) + (nf << 11) + low1);
    }
    STAGE_A(1, t + 1);
    __builtin_amdgcn_s_setprio(1);
#pragma unroll
    for (int mf = 0; mf < 4; ++mf)
#pragma unroll
      for (int nf = 0; nf < 2; ++nf) {
        acc[mf][2 + nf] = MFMA16(a0[mf][0], b1[nf][0], acc[mf][2 + nf]);
        acc[mf][2 + nf] = MFMA16(a0[mf][1], b1[nf][1], acc[mf][2 + nf]);
      }
    __builtin_amdgcn_s_setprio(0);
    asm volatile("s_barrier" ::: "memory");

    // ---- ph2 ----
#pragma unroll
    for (int mf = 0; mf < 4; ++mf) {
      a1[mf][0] = *(const bf16x8*)(aSm + aBase + (1 << 13) + (mf << 11) + low0);
      a1[mf][1] = *(const bf16x8*)(aSm + aBase + (1 << 13) + (mf << 11) + low1);
    }
    STAGE_B(0, t + 2);
    __builtin_amdgcn_s_setprio(1);
#pragma unroll
    for (int mf = 0; mf < 4; ++mf)
#pragma unroll
      for (int nf = 0; nf < 2; ++nf) {
        acc[4 + mf][nf] = MFMA16(a1[mf][0], b0[nf][0], acc[4 + mf][nf]);
        acc[4 + mf][nf] = MFMA16(a1[mf][1], b0[nf][1], acc[4 + mf][nf]);
      }
    __builtin_amdgcn_s_setprio(0);
    asm volatile("s_barrier" ::: "memory");

    // ---- ph3 ----
    STAGE_B(1, t + 2);
    __builtin_amdgcn_s_setprio(1);
#pragma unroll
    for (int mf = 0; mf < 4; ++mf)
#pragma unroll
      for (int nf = 0; nf < 2; ++nf) {
        acc[4 + mf][2 + nf] = MFMA16(a1[mf][0], b1[nf][0], acc[4 + mf][2 + nf]);
        acc[4 + mf][2 + nf] = MFMA16(a1[mf][1], b1[nf][1], acc[4 + mf][2 + nf]);
      }
    __builtin_amdgcn_s_setprio(0);
  }

  if (MODE != 2) {
    // ---- plain epilogue ----
#pragma unroll
    for (int g = 0; g < 2; ++g)
#pragma unroll
      for (int mf = 0; mf < 4; ++mf)
#pragma unroll
        for (int ng = 0; ng < 2; ++ng)
#pragma unroll
          for (int nfi = 0; nfi < 2; ++nfi) {
            const f32x4 v = acc[g * 4 + mf][ng * 2 + nfi];
            const int row0 = m0 + wm * 128 + g * 64 + mf * 16 + hi * 4;
            const int col = n0 + wn * 64 + ng * 32 + nfi * 16 + lo;
            if (MODE == 1) {
              const float bb = bias[col];
#pragma unroll
              for (int r = 0; r < 4; ++r)
                Cf[(size_t)(row0 + r) * N + col] = v[r] + bb;
            } else {
#pragma unroll
              for (int r = 0; r < 4; ++r)
                Cb[(size_t)(row0 + r) * N + col] = f2bf(v[r]);
            }
          }
  } else {
    // ---- fused attention epilogue ----
    // Drain in-flight global_load_lds (they would corrupt Q-LDS), sync all waves.
    asm volatile("s_waitcnt vmcnt(0)" ::: "memory");
    __builtin_amdgcn_s_barrier();

    // Wave-private Q chunk: [128 q][64 d], stride 66 u16 (pad vs bank conflicts).
    u16* qlds = smem + w * 8448;
#pragma unroll
    for (int g = 0; g < 2; ++g)
#pragma unroll
      for (int mf = 0; mf < 4; ++mf)
#pragma unroll
        for (int ng = 0; ng < 2; ++ng)
#pragma unroll
          for (int nfi = 0; nfi < 2; ++nfi) {
            const f32x4 v = acc[g * 4 + mf][ng * 2 + nfi];
            const int qrow = g * 64 + mf * 16 + hi * 4;
            const int d = ng * 32 + nfi * 16 + lo;
#pragma unroll
            for (int r = 0; r < 4; ++r) qlds[(qrow + r) * 66 + d] = f2bf(v[r]);
          }

    const int l31 = lane & 31, hi5 = lane >> 5;
    const int h = bn * 4 + wn;       // this wave's head
    const int b = m0 >> 12;          // batch (4096 rows per batch)
    const u16* vbase = vtP + ((size_t)(b * 20 + h) * 64) * 96 + hi5 * 8;
    const int rowB = m0 + wm * 128;  // global row of this wave's q0

#pragma unroll
    for (int pass = 0; pass < 2; ++pass) {
      bf16x8 qf0[4], qf1[4];
#pragma unroll
      for (int dc = 0; dc < 4; ++dc) {
        qf0[dc] = *(const bf16x8*)&qlds[(pass * 64 + l31) * 66 + dc * 16 + hi5 * 8];
        qf1[dc] = *(const bf16x8*)&qlds[(pass * 64 + 32 + l31) * 66 + dc * 16 + hi5 * 8];
      }

      f32x16 s0[3], s1[3];
#pragma unroll
      for (int kf = 0; kf < 3; ++kf)
#pragma unroll
        for (int r = 0; r < 16; ++r) { s0[kf][r] = 0.f; s1[kf][r] = 0.f; }

#pragma unroll
      for (int kf = 0; kf < 3; ++kf) {
        const int key = kf * 32 + l31;
        const u16* kp;
        if (key < 77) kp = kvcP + (size_t)(b * 77 + key) * 5120 + h * 64 + hi5 * 8;
        else if (key >= 80 && key < 84)
          kp = kvcP + (size_t)(640 + b * 4 + key - 80) * 5120 + 2560 + h * 64 + hi5 * 8;
        else kp = kvcP + h * 64 + hi5 * 8;  // masked later
        bf16x8 ka[4];
#pragma unroll
        for (int dc = 0; dc < 4; ++dc) ka[dc] = *(const bf16x8*)(kp + dc * 16);
#pragma unroll
        for (int dc = 0; dc < 4; ++dc) {
          s0[kf] = MFMA32(ka[dc], qf0[dc], s0[kf]);
          s1[kf] = MFMA32(ka[dc], qf1[dc], s1[kf]);
        }
      }

      float st0 = 0.f, si0 = 0.f, st1 = 0.f, si1 = 0.f;
#pragma unroll
      for (int kf = 0; kf < 3; ++kf)
#pragma unroll
        for (int r = 0; r < 16; ++r) {
          const int krem = (r & 3) + 8 * (r >> 2);
          const int k = kf * 32 + krem + 4 * hi5;
          const bool vtx = k < 77;
          const bool vip = (k >= 80) & (k < 84);
          const float e0 = (vtx | vip) ? __expf(s0[kf][r] * 0.125f) : 0.f;
          const float e1 = (vtx | vip) ? __expf(s1[kf][r] * 0.125f) : 0.f;
          s0[kf][r] = e0; s1[kf][r] = e1;
          st0 += vtx ? e0 : 0.f; si0 += vip ? e0 : 0.f;
          st1 += vtx ? e1 : 0.f; si1 += vip ? e1 : 0.f;
        }
      st0 += __shfl_xor(st0, 32); si0 += __shfl_xor(si0, 32);
      st1 += __shfl_xor(st1, 32); si1 += __shfl_xor(si1, 32);
      const float rt0 = __fdividef(1.f, st0), ri0 = __fdividef(1.f, si0);
      const float rt1 = __fdividef(1.f, st1), ri1 = __fdividef(1.f, si1);
#pragma unroll
      for (int kf = 0; kf < 3; ++kf)
#pragma unroll
        for (int r = 0; r < 16; ++r) {
          const int krem = (r & 3) + 8 * (r >> 2);
          const int k = kf * 32 + krem + 4 * hi5;
          const bool vip = (k >= 80) & (k < 84);
          s0[kf][r] *= vip ? ri0 : rt0;
          s1[kf][r] *= vip ? ri1 : rt1;
        }

#define PV_STORE(sA, qoff)                                                  \
      {                                                                     \
        f32x16 pacc[2];                                                     \
        _Pragma("unroll") for (int nf = 0; nf < 2; ++nf)                    \
        _Pragma("unroll") for (int r = 0; r < 16; ++r) pacc[nf][r] = 0.f;   \
        _Pragma("unroll") for (int ks = 0; ks < 6; ++ks) {                  \
          const int kf = ks >> 1;                                           \
          const int rb = (ks & 1) * 8;                                      \
          const u32 lo01 = cvtpk(sA[kf][rb + 0], sA[kf][rb + 1]);           \
          const u32 lo23 = cvtpk(sA[kf][rb + 2], sA[kf][rb + 3]);           \
          const u32 hi01 = cvtpk(sA[kf][rb + 4], sA[kf][rb + 5]);           \
          const u32 hi23 = cvtpk(sA[kf][rb + 6], sA[kf][rb + 7]);           \
          const u32 plo01 = __shfl_xor(lo01, 32);                           \
          const u32 plo23 = __shfl_xor(lo23, 32);                           \
          const u32 phi01 = __shfl_xor(hi01, 32);                           \
          const u32 phi23 = __shfl_xor(hi23, 32);                           \
          union { u32 u[4]; bf16x8 v; } pu;                                 \
          pu.u[0] = hi5 ? phi01 : lo01;                                     \
          pu.u[1] = hi5 ? phi23 : lo23;                                     \
          pu.u[2] = hi5 ? hi01 : plo01;                                     \
          pu.u[3] = hi5 ? hi23 : plo23;                                     \
          _Pragma("unroll") for (int nf = 0; nf < 2; ++nf) {                \
            const bf16x8 vb = *(const bf16x8*)(vbase +                      \
                (size_t)(nf * 32 + l31) * 96 + ks * 16);                    \
            pacc[nf] = MFMA32(pu.v, vb, pacc[nf]);                          \
          }                                                                 \
        }                                                                   \
        _Pragma("unroll") for (int nf = 0; nf < 2; ++nf)                    \
        _Pragma("unroll") for (int r = 0; r < 16; ++r) {                    \
          const int row = rowB + pass * 64 + (qoff) +                       \
                          (r & 3) + 8 * (r >> 2) + 4 * hi5;                 \
          Cb[(size_t)row * 1280 + h * 64 + nf * 32 + l31] =                 \
              f2bf(pacc[nf][r]);                                            \
        }                                                                   \
      }

      PV_STORE(s0, 0)
      PV_STORE(s1, 32)
#undef PV_STORE
    }
  }
#undef STAGE_A
#undef STAGE_B
}

// ---------------- VT build: vt[b*20+h][d=64][k=96] from kvc V columns ----------------
__global__ __launch_bounds__(256) void build_vt(const u16* __restrict__ kvc,
                                                u16* __restrict__ vt) {
  __shared__ u16 Ls[96][72];
  const int tid = threadIdx.x;
  const int h = blockIdx.x % 20, b = blockIdx.x / 20;
  for (int idx = tid; idx < 96 * 8; idx += 256) {
    const int row = idx >> 3, c8 = (idx & 7) << 3;
    uint4 val = make_uint4(0, 0, 0, 0);
    if (row < 77)
      val = *(const uint4*)(kvc + (size_t)(b * 77 + row) * 5120 + 1280 + h * 64 + c8);
    else if (row >= 80 && row < 84)
      val = *(const uint4*)(kvc + (size_t)(640 + b * 4 + row - 80) * 5120 + 3840 + h * 64 + c8);
    *(uint4*)&Ls[row][c8] = val;
  }
  __syncthreads();
  u16* dst = vt + (size_t)blockIdx.x * 64 * 96;
  for (int idx = tid; idx < 768; idx += 256) {
    const int d = idx / 12, c = (idx % 12) * 8;
    u16 tmp[8];
#pragma unroll
    for (int j = 0; j < 8; ++j) tmp[j] = Ls[c + j][d];
    *(uint4*)(dst + d * 96 + c) = *(const uint4*)tmp;
  }
}

// ---------------- launch ----------------
extern "C" void kernel_launch(void* const* d_in, const int* in_sizes, int n_in,
                              void* d_out, int out_size, void* d_ws, size_t ws_size,
                              hipStream_t stream) {
  (void)in_sizes; (void)n_in; (void)out_size; (void)ws_size;
  const float* hs   = (const float*)d_in[0];
  const float* enc  = (const float*)d_in[1];
  const float* ip   = (const float*)d_in[2];
  const float* Wq   = (const float*)d_in[3];
  const float* Wk   = (const float*)d_in[4];
  const float* Wv   = (const float*)d_in[5];
  const float* Wkip = (const float*)d_in[6];
  const float* Wvip = (const float*)d_in[7];
  const float* Wo   = (const float*)d_in[8];
  const float* bo   = (const float*)d_in[9];
  float* out = (float*)d_out;

  // d_out (167.8 MB) as scratch: wq_t at start, hs_bf in second half
  // (both dead before the final f32 output write by O-proj).
  u16* wq_t  = (u16*)d_out;                        // 3,276,800 B
  u16* hs_bf = (u16*)d_out + 41943040;             // 83,886,080 B

  // ws layout. kvw/a_all overlap the attn region (dead before fused kernel).
  char* ws = (char*)d_ws;
  u16* kvc   = (u16*)(ws);                          // 15,728,640 B  [768][5120]
  u16* wo_t  = (u16*)(ws + 15728640);               //  3,276,800 B
  u16* vt    = (u16*)(ws + 19005440);               //  1,966,080 B  [160][64][96]
  u16* attn  = (u16*)(ws + 20971520);               // 83,886,080 B
  u16* kvw   = (u16*)(ws + 20971520 + 3276800);     // 20,971,520 B (overlap) [5120][2048]
  u16* a_all = (u16*)(ws + 20971520 + 24248320);    //  3,145,728 B (overlap) [768][2048]

  f32_to_bf16_vec<<<40960, 256, 0, stream>>>(hs, hs_bf, 10485760);
  build_a_all<<<1536, 256, 0, stream>>>(enc, ip, a_all);

  dim3 tb(32, 8);
  transpose_w4<<<dim3(40, 64, 4), tb, 0, stream>>>(Wk, Wv, Wkip, Wvip, kvw);
  transpose_w2<<<dim3(40, 40, 2), tb, 0, stream>>>(Wq, Wo, wq_t, wo_t);

  // fused K/V projections first (fused Q-proj+attn needs kvc & vt ready)
  gemm256<0><<<60, 512, 0, stream>>>(a_all, kvw, kvc, nullptr, nullptr, nullptr, nullptr,
                                     768, 5120, 2048);
  build_vt<<<160, 256, 0, stream>>>(kvc, vt);

  // Q-proj + attention fused: writes attn directly
  gemm256<2><<<640, 512, 0, stream>>>(hs_bf, wq_t, attn, nullptr, nullptr, kvc, vt,
                                      32768, 1280, 1280);

  // O-proj + bias (f32 out)
  gemm256<1><<<640, 512, 0, stream>>>(attn, wo_t, nullptr, out, bo, nullptr, nullptr,
                                      32768, 1280, 1280);
}